// Round 1
// baseline (1765.715 us; speedup 1.0000x reference)
//
#include <hip/hip_runtime.h>
#include <math.h>

// ProxyNCA loss on MI355X.
// nll_i = log(sum_c exp(s_ic)) - s_{i,T_i},  s_ic = q[c] * dot(Xs_i, prox_c),
// Xs = 3*normalize(X), q[c] = 6/||prox_c||.
// Round 0: fp32 VALU baseline (correctness-first). ~220us FMA floor.

#define NROWS 4096
#define NCLS  65536
#define DIM   64
#define RTILE 64      // rows per block
#define CTILE 64      // classes per LDS tile
#define SPLITS 8      // class splits (blocks = 64 row-tiles * 8 = 512 = 2/CU)
#define CSPLIT (NCLS / SPLITS)   // 8192 classes per block

// ---- normalize X rows: Xs = 3 * x / max(||x||, 1e-12) -------------------
__global__ void k_norm_x(const float* __restrict__ X, float* __restrict__ Xs) {
    int row  = blockIdx.x * 4 + (threadIdx.x >> 6);
    int lane = threadIdx.x & 63;
    float v  = X[row * DIM + lane];
    float sq = v * v;
    #pragma unroll
    for (int off = 32; off > 0; off >>= 1) sq += __shfl_xor(sq, off);
    float rn = 3.0f / fmaxf(sqrtf(sq), 1e-12f);
    Xs[row * DIM + lane] = v * rn;
}

// ---- per-class scale: q[c] = 6 / max(||p_c||, 1e-12) --------------------
__global__ void k_norm_p(const float* __restrict__ P, float* __restrict__ q) {
    int row  = blockIdx.x * 4 + (threadIdx.x >> 6);
    int lane = threadIdx.x & 63;
    float v  = P[row * DIM + lane];
    float sq = v * v;
    #pragma unroll
    for (int off = 32; off > 0; off >>= 1) sq += __shfl_xor(sq, off);
    if (lane == 0) q[row] = 6.0f / fmaxf(sqrtf(sq), 1e-12f);
}

// ---- main: per (row-tile, class-split): partial sum(exp(s)) + target s --
// thread t: row r = rt*64 + (t&63), wave g = t>>6 handles classes g*16+j.
// All 64 lanes of a wave share g -> LDS P reads are pure broadcast.
__global__ __launch_bounds__(256, 2)
void k_main(const float* __restrict__ Xs, const float* __restrict__ prox,
            const float* __restrict__ q, const int* __restrict__ T,
            float* __restrict__ psum, float* __restrict__ pst) {
    __shared__ float4 pbuf[CTILE * 16];   // 16 KB: 64 classes x 64 dims
    __shared__ float  qbuf[CTILE];
    __shared__ float  redS[256];
    __shared__ float  redT[256];

    int bx    = blockIdx.x;
    int rt    = bx & 63;
    int split = bx >> 6;
    int t     = threadIdx.x;
    int r     = rt * RTILE + (t & 63);
    int g     = t >> 6;

    float4 xs[16];
    #pragma unroll
    for (int i = 0; i < 16; ++i)
        xs[i] = reinterpret_cast<const float4*>(Xs)[r * 16 + i];
    int Tr = T[r];

    const float4* prox4 = reinterpret_cast<const float4*>(prox);

    float ssum = 0.0f;
    float st   = 0.0f;
    int cbase0 = split * CSPLIT;

    for (int ct = 0; ct < CSPLIT; ct += CTILE) {
        int cbase = cbase0 + ct;
        #pragma unroll
        for (int j = 0; j < 4; ++j) {
            int idx = t + j * 256;
            pbuf[idx] = prox4[cbase * 16 + idx];   // coalesced 16B/lane
        }
        if (t < CTILE) qbuf[t] = q[cbase + t];
        __syncthreads();

        #pragma unroll
        for (int j = 0; j < 16; ++j) {
            int cl = g * 16 + j;
            float4 a = {0.f, 0.f, 0.f, 0.f};
            #pragma unroll
            for (int k = 0; k < 16; ++k) {
                float4 p = pbuf[cl * 16 + k];      // wave-broadcast
                a.x += xs[k].x * p.x;  a.y += xs[k].y * p.y;
                a.z += xs[k].z * p.z;  a.w += xs[k].w * p.w;
            }
            float dot = (a.x + a.y) + (a.z + a.w);
            float s = qbuf[cl] * dot;
            ssum += __expf(s);
            if (cbase + cl == Tr) st = s;
        }
        __syncthreads();
    }

    redS[t] = ssum;
    redT[t] = st;
    __syncthreads();
    if (t < 64) {
        float tot = redS[t] + redS[t + 64] + redS[t + 128] + redS[t + 192];
        float stt = redT[t] + redT[t + 64] + redT[t + 128] + redT[t + 192];
        psum[split * NROWS + rt * RTILE + t] = tot;
        pst [split * NROWS + rt * RTILE + t] = stt;
    }
}

// ---- final: nll_i = log(sum over splits) - s_t;  out = mean ------------
__global__ void k_final(const float* __restrict__ psum,
                        const float* __restrict__ pst,
                        float* __restrict__ out) {
    __shared__ float red[256];
    int t = threadIdx.x;
    float acc = 0.0f;
    for (int r = t; r < NROWS; r += 256) {
        float tot = 0.0f, st = 0.0f;
        #pragma unroll
        for (int s = 0; s < SPLITS; ++s) {
            tot += psum[s * NROWS + r];
            st  += pst [s * NROWS + r];
        }
        acc += logf(tot) - st;
    }
    red[t] = acc;
    __syncthreads();
    #pragma unroll
    for (int off = 128; off > 0; off >>= 1) {
        if (t < off) red[t] += red[t + off];
        __syncthreads();
    }
    if (t == 0) out[0] = red[0] / (float)NROWS;
}

extern "C" void kernel_launch(void* const* d_in, const int* in_sizes, int n_in,
                              void* d_out, int out_size, void* d_ws, size_t ws_size,
                              hipStream_t stream) {
    const float* X  = (const float*)d_in[0];
    const float* P  = (const float*)d_in[1];
    const int*   T  = (const int*)  d_in[3];   // d_in[2] = indices (unused)
    float* out = (float*)d_out;

    char* ws = (char*)d_ws;
    float* Xs   = (float*)ws;                              // 1 MB
    float* q    = (float*)(ws + (1 << 20));                // 256 KB
    float* psum = (float*)(ws + (1 << 20) + (256 << 10));  // 128 KB
    float* pst  = psum + SPLITS * NROWS;                   // 128 KB

    k_norm_x<<<NROWS / 4, 256, 0, stream>>>(X, Xs);
    k_norm_p<<<NCLS / 4, 256, 0, stream>>>(P, q);
    k_main<<<SPLITS * (NROWS / RTILE), 256, 0, stream>>>(Xs, P, q, T, psum, pst);
    k_final<<<1, 256, 0, stream>>>(psum, pst, out);
}

// Round 2
// 153.184 us; speedup vs baseline: 11.5267x; 11.5267x over previous
//
#include <hip/hip_runtime.h>
#include <math.h>

// ProxyNCA loss, MFMA version.
// logit_ic = 18 * xhat_i . phat_c ;  nll_i = log(sum_c exp(logit_ic)) - logit_{i,T_i}
// Trick: prescale both operands by sqrt(18*log2(e)) = 5.0959308 and convert to bf16;
// then the 16x16x32 bf16 MFMA accumulator directly holds log2(e)*logit, so
// exp(logit) == exp2f(acc): hot loop is v_exp_f32 + v_add only.
// Target logit s_T computed in separate exact-f32 kernel.

#define NROWS 4096
#define NCLS  65536
#define DIM   64
#define CBLK  128                 // classes per block (register-resident B frags)
#define NBLK  (NCLS / CBLK)       // 512 blocks = 2/CU
#define NCH   (CBLK / 16)         // 8 MFMA chunks of 16 classes

typedef __attribute__((ext_vector_type(8))) short short8;
typedef __attribute__((ext_vector_type(4))) float f32x4;

#define PRESCALE 5.0959308f       // sqrt(18 * log2(e))

__device__ __forceinline__ short bf16rne(float f) {
    union { float f; unsigned u; } v; v.f = f;
    unsigned r = (v.u + 0x7fffu + ((v.u >> 16) & 1u)) >> 16;
    return (short)r;
}

// ---- Xs_bf16 = bf16( PRESCALE * x / max(||x||,1e-12) ) ------------------
__global__ void k_prep_x(const float* __restrict__ X, unsigned short* __restrict__ Xb) {
    int row  = blockIdx.x * 4 + (threadIdx.x >> 6);
    int lane = threadIdx.x & 63;
    float v  = X[row * DIM + lane];
    float sq = v * v;
    #pragma unroll
    for (int off = 32; off > 0; off >>= 1) sq += __shfl_xor(sq, off);
    float rn = PRESCALE / fmaxf(sqrtf(sq), 1e-12f);
    Xb[row * DIM + lane] = (unsigned short)bf16rne(v * rn);
}

// ---- exact-f32 target logit: st[r] = 18 * (x_r . p_{T_r}) / (||x|| ||p||) ----
__global__ void k_target(const float* __restrict__ X, const float* __restrict__ P,
                         const int* __restrict__ T, float* __restrict__ st) {
    int row  = blockIdx.x * 4 + (threadIdx.x >> 6);
    int lane = threadIdx.x & 63;
    int tc   = T[row];
    float xv = X[row * DIM + lane];
    float pv = P[tc  * DIM + lane];
    float x2 = xv * xv, p2 = pv * pv, xp = xv * pv;
    #pragma unroll
    for (int off = 32; off > 0; off >>= 1) {
        x2 += __shfl_xor(x2, off);
        p2 += __shfl_xor(p2, off);
        xp += __shfl_xor(xp, off);
    }
    if (lane == 0)
        st[row] = 18.0f * xp * rsqrtf(fmaxf(x2, 1e-24f)) * rsqrtf(fmaxf(p2, 1e-24f));
}

// ---- main: block b owns classes [b*128,(b+1)*128); sweeps all 4096 rows ----
// 8 waves; wave w handles row-tiles w, w+8, ... (32 tiles of 16 rows).
// B frags (P side) normalized/converted once into 64 VGPRs per wave.
// mfma(P_frag, X_frag): C col = lane&15 = x-row, regs = 4 classes.
__global__ __launch_bounds__(512, 4)
void k_main(const float* __restrict__ prox, const unsigned short* __restrict__ Xb,
            float* __restrict__ psum) {
    int t = threadIdx.x;
    int w = t >> 6;
    int l = t & 63;
    int cb = blockIdx.x * CBLK;

    int lm = l & 15;         // class-in-chunk (A row) / x-row (B col)
    int lk = l >> 4;         // k-group

    // ---- one-time: load 128 classes of P (f32), normalize, convert to frags
    short8 pb[NCH][2];
    #pragma unroll
    for (int ch = 0; ch < NCH; ++ch) {
        int cls = cb + ch * 16 + lm;
        const float4* pr = reinterpret_cast<const float4*>(prox + cls * DIM + lk * 8);
        float4 a0 = pr[0], a1 = pr[1];          // k = lk*8 .. +7
        const float4* pr2 = reinterpret_cast<const float4*>(prox + cls * DIM + 32 + lk * 8);
        float4 b0 = pr2[0], b1 = pr2[1];        // k = 32 + lk*8 .. +7
        float sq = a0.x*a0.x + a0.y*a0.y + a0.z*a0.z + a0.w*a0.w
                 + a1.x*a1.x + a1.y*a1.y + a1.z*a1.z + a1.w*a1.w
                 + b0.x*b0.x + b0.y*b0.y + b0.z*b0.z + b0.w*b0.w
                 + b1.x*b1.x + b1.y*b1.y + b1.z*b1.z + b1.w*b1.w;
        sq += __shfl_xor(sq, 16);
        sq += __shfl_xor(sq, 32);
        float sc = PRESCALE * rsqrtf(fmaxf(sq, 1e-24f));
        short8 f0, f1;
        f0[0]=bf16rne(a0.x*sc); f0[1]=bf16rne(a0.y*sc); f0[2]=bf16rne(a0.z*sc); f0[3]=bf16rne(a0.w*sc);
        f0[4]=bf16rne(a1.x*sc); f0[5]=bf16rne(a1.y*sc); f0[6]=bf16rne(a1.z*sc); f0[7]=bf16rne(a1.w*sc);
        f1[0]=bf16rne(b0.x*sc); f1[1]=bf16rne(b0.y*sc); f1[2]=bf16rne(b0.z*sc); f1[3]=bf16rne(b0.w*sc);
        f1[4]=bf16rne(b1.x*sc); f1[5]=bf16rne(b1.y*sc); f1[6]=bf16rne(b1.z*sc); f1[7]=bf16rne(b1.w*sc);
        pb[ch][0] = f0;
        pb[ch][1] = f1;
    }

    // ---- row sweep
    for (int tile = w; tile < NROWS / 16; tile += 8) {
        int rowbase = tile * 16;
        const short8* xr0 = reinterpret_cast<const short8*>(Xb + (rowbase + lm) * DIM + lk * 8);
        const short8* xr1 = reinterpret_cast<const short8*>(Xb + (rowbase + lm) * DIM + 32 + lk * 8);
        short8 xb0 = *xr0;
        short8 xb1 = *xr1;

        float eacc0 = 0.0f, eacc1 = 0.0f;
        #pragma unroll
        for (int ch = 0; ch < NCH; ++ch) {
            f32x4 c = {0.0f, 0.0f, 0.0f, 0.0f};
            c = __builtin_amdgcn_mfma_f32_16x16x32_bf16(pb[ch][0], xb0, c, 0, 0, 0);
            c = __builtin_amdgcn_mfma_f32_16x16x32_bf16(pb[ch][1], xb1, c, 0, 0, 0);
            // c[j] = log2(e) * logit for class (cb+ch*16+lk*4+j), row (rowbase+lm)
            eacc0 += exp2f(c[0]) + exp2f(c[1]);
            eacc1 += exp2f(c[2]) + exp2f(c[3]);
        }
        float eacc = eacc0 + eacc1;
        eacc += __shfl_xor(eacc, 16);
        eacc += __shfl_xor(eacc, 32);
        if (l < 16) psum[blockIdx.x * NROWS + rowbase + l] = eacc;
    }
}

// ---- per-row: nll[r] = log(sum_b psum[b][r]) - st[r] --------------------
__global__ void k_rowred(const float* __restrict__ psum, const float* __restrict__ st,
                         float* __restrict__ nll) {
    __shared__ float red[256];
    int t = threadIdx.x;
    int r = blockIdx.x * 64 + (t & 63);
    int q = t >> 6;                     // 4 partial groups of 128 blocks
    float s = 0.0f;
    for (int i = q * 128; i < q * 128 + 128; ++i)
        s += psum[i * NROWS + r];
    red[t] = s;
    __syncthreads();
    if (t < 64) {
        float tot = red[t] + red[t + 64] + red[t + 128] + red[t + 192];
        nll[blockIdx.x * 64 + t] = logf(tot) - st[blockIdx.x * 64 + t];
    }
}

// ---- mean over rows -----------------------------------------------------
__global__ void k_final(const float* __restrict__ nll, float* __restrict__ out) {
    __shared__ float red[256];
    int t = threadIdx.x;
    float acc = 0.0f;
    for (int r = t; r < NROWS; r += 256) acc += nll[r];
    red[t] = acc;
    __syncthreads();
    #pragma unroll
    for (int off = 128; off > 0; off >>= 1) {
        if (t < off) red[t] += red[t + off];
        __syncthreads();
    }
    if (t == 0) out[0] = red[0] / (float)NROWS;
}

extern "C" void kernel_launch(void* const* d_in, const int* in_sizes, int n_in,
                              void* d_out, int out_size, void* d_ws, size_t ws_size,
                              hipStream_t stream) {
    const float* X = (const float*)d_in[0];
    const float* P = (const float*)d_in[1];
    const int*   T = (const int*)  d_in[3];   // d_in[2] = indices (unused)
    float* out = (float*)d_out;

    char* ws = (char*)d_ws;
    unsigned short* Xb = (unsigned short*)ws;                 // 512 KB
    float* st   = (float*)(ws + (512 << 10));                 // 16 KB
    float* nll  = (float*)(ws + (512 << 10) + (16 << 10));    // 16 KB
    float* psum = (float*)(ws + (1 << 20));                   // 8 MB (512 x 4096 f32)

    k_prep_x<<<NROWS / 4, 256, 0, stream>>>(X, Xb);
    k_target<<<NROWS / 4, 256, 0, stream>>>(X, P, T, st);
    k_main  <<<NBLK, 512, 0, stream>>>(P, Xb, psum);
    k_rowred<<<NROWS / 64, 256, 0, stream>>>(psum, st, nll);
    k_final <<<1, 256, 0, stream>>>(nll, out);
}

// Round 3
// 113.986 us; speedup vs baseline: 15.4906x; 1.3439x over previous
//
#include <hip/hip_runtime.h>
#include <math.h>

// ProxyNCA loss, MFMA version.
// logit_ic = 18 * xhat_i . phat_c ;  nll_i = log(sum_c exp(logit_ic)) - logit_{i,T_i}
// Prescale both operands by sqrt(18*log2(e)) = 5.0959308, convert to bf16;
// the 16x16x32 bf16 MFMA accumulator then holds log2(e)*logit directly, so
// exp(logit) == v_exp_f32(acc): hot loop = MFMA + v_exp + v_add only.
// Round 3 fixes vs round 2:
//  - exp2f -> __builtin_amdgcn_exp2f (OCML exp2f was ~12 VALU instrs/elem)
//  - __launch_bounds__(512,2): round 2's (512,4) capped unified VGPR+AGPR at
//    128 -> pb fragments spilled to scratch (WRITE_SIZE 61MB vs 8MB psum).
//  - k_prep_x + k_target merged (one less launch).

#define NROWS 4096
#define NCLS  65536
#define DIM   64
#define CBLK  128                 // classes per block (register-resident B frags)
#define NBLK  (NCLS / CBLK)       // 512 blocks = 2/CU
#define NCH   (CBLK / 16)         // 8 MFMA chunks of 16 classes

typedef __attribute__((ext_vector_type(8))) short short8;
typedef __attribute__((ext_vector_type(4))) float f32x4;

#define PRESCALE 5.0959308f       // sqrt(18 * log2(e))

__device__ __forceinline__ short bf16rne(float f) {
    union { float f; unsigned u; } v; v.f = f;
    unsigned r = (v.u + 0x7fffu + ((v.u >> 16) & 1u)) >> 16;
    return (short)r;
}

// ---- per-row prep: Xb = bf16(PRESCALE * xhat), st[r] = exact f32 target logit
__global__ void k_prep(const float* __restrict__ X, const float* __restrict__ P,
                       const int* __restrict__ T,
                       unsigned short* __restrict__ Xb, float* __restrict__ st) {
    int row  = blockIdx.x * 4 + (threadIdx.x >> 6);
    int lane = threadIdx.x & 63;
    int tc   = T[row];
    float xv = X[row * DIM + lane];
    float pv = P[tc  * DIM + lane];
    float x2 = xv * xv, p2 = pv * pv, xp = xv * pv;
    #pragma unroll
    for (int off = 32; off > 0; off >>= 1) {
        x2 += __shfl_xor(x2, off);
        p2 += __shfl_xor(p2, off);
        xp += __shfl_xor(xp, off);
    }
    float rx = rsqrtf(fmaxf(x2, 1e-24f));
    Xb[row * DIM + lane] = (unsigned short)bf16rne(xv * (PRESCALE * rx));
    if (lane == 0)
        st[row] = 18.0f * xp * rx * rsqrtf(fmaxf(p2, 1e-24f));
}

// ---- main: block b owns classes [b*128,(b+1)*128); sweeps all 4096 rows ----
// 8 waves; wave w handles row-tiles w, w+8, ... (32 tiles of 16 rows).
// B frags (P side) normalized/converted once into 64 regs per wave.
// mfma(P_frag, X_frag): C col = lane&15 = x-row, regs = 4 classes.
__global__ __launch_bounds__(512, 2)
void k_main(const float* __restrict__ prox, const unsigned short* __restrict__ Xb,
            float* __restrict__ psum) {
    int t = threadIdx.x;
    int w = t >> 6;
    int l = t & 63;
    int cb = blockIdx.x * CBLK;

    int lm = l & 15;         // class-in-chunk (A row) / x-row (B col)
    int lk = l >> 4;         // k-group

    // ---- one-time: load 128 classes of P (f32), normalize, convert to frags
    short8 pb[NCH][2];
    #pragma unroll
    for (int ch = 0; ch < NCH; ++ch) {
        int cls = cb + ch * 16 + lm;
        const float4* pr = reinterpret_cast<const float4*>(prox + cls * DIM + lk * 8);
        float4 a0 = pr[0], a1 = pr[1];          // k = lk*8 .. +7
        const float4* pr2 = reinterpret_cast<const float4*>(prox + cls * DIM + 32 + lk * 8);
        float4 b0 = pr2[0], b1 = pr2[1];        // k = 32 + lk*8 .. +7
        float sq = a0.x*a0.x + a0.y*a0.y + a0.z*a0.z + a0.w*a0.w
                 + a1.x*a1.x + a1.y*a1.y + a1.z*a1.z + a1.w*a1.w
                 + b0.x*b0.x + b0.y*b0.y + b0.z*b0.z + b0.w*b0.w
                 + b1.x*b1.x + b1.y*b1.y + b1.z*b1.z + b1.w*b1.w;
        sq += __shfl_xor(sq, 16);
        sq += __shfl_xor(sq, 32);
        float sc = PRESCALE * rsqrtf(fmaxf(sq, 1e-24f));
        short8 f0, f1;
        f0[0]=bf16rne(a0.x*sc); f0[1]=bf16rne(a0.y*sc); f0[2]=bf16rne(a0.z*sc); f0[3]=bf16rne(a0.w*sc);
        f0[4]=bf16rne(a1.x*sc); f0[5]=bf16rne(a1.y*sc); f0[6]=bf16rne(a1.z*sc); f0[7]=bf16rne(a1.w*sc);
        f1[0]=bf16rne(b0.x*sc); f1[1]=bf16rne(b0.y*sc); f1[2]=bf16rne(b0.z*sc); f1[3]=bf16rne(b0.w*sc);
        f1[4]=bf16rne(b1.x*sc); f1[5]=bf16rne(b1.y*sc); f1[6]=bf16rne(b1.z*sc); f1[7]=bf16rne(b1.w*sc);
        pb[ch][0] = f0;
        pb[ch][1] = f1;
    }

    // ---- row sweep
    for (int tile = w; tile < NROWS / 16; tile += 8) {
        int rowbase = tile * 16;
        const short8* xr0 = reinterpret_cast<const short8*>(Xb + (rowbase + lm) * DIM + lk * 8);
        const short8* xr1 = reinterpret_cast<const short8*>(Xb + (rowbase + lm) * DIM + 32 + lk * 8);
        short8 xb0 = *xr0;
        short8 xb1 = *xr1;

        float eacc0 = 0.0f, eacc1 = 0.0f;
        #pragma unroll
        for (int ch = 0; ch < NCH; ++ch) {
            f32x4 c = {0.0f, 0.0f, 0.0f, 0.0f};
            c = __builtin_amdgcn_mfma_f32_16x16x32_bf16(pb[ch][0], xb0, c, 0, 0, 0);
            c = __builtin_amdgcn_mfma_f32_16x16x32_bf16(pb[ch][1], xb1, c, 0, 0, 0);
            // c[j] = log2(e) * logit for class (cb+ch*16+lk*4+j), row (rowbase+lm)
            eacc0 += __builtin_amdgcn_exp2f(c[0]) + __builtin_amdgcn_exp2f(c[1]);
            eacc1 += __builtin_amdgcn_exp2f(c[2]) + __builtin_amdgcn_exp2f(c[3]);
        }
        float eacc = eacc0 + eacc1;
        eacc += __shfl_xor(eacc, 16);
        eacc += __shfl_xor(eacc, 32);
        if (l < 16) psum[blockIdx.x * NROWS + rowbase + l] = eacc;
    }
}

// ---- per-row: nll[r] = log(sum_b psum[b][r]) - st[r] --------------------
__global__ void k_rowred(const float* __restrict__ psum, const float* __restrict__ st,
                         float* __restrict__ nll) {
    __shared__ float red[256];
    int t = threadIdx.x;
    int r = blockIdx.x * 64 + (t & 63);
    int q = t >> 6;                     // 4 partial groups of 128 blocks
    float s = 0.0f;
    for (int i = q * 128; i < q * 128 + 128; ++i)
        s += psum[i * NROWS + r];
    red[t] = s;
    __syncthreads();
    if (t < 64) {
        float tot = red[t] + red[t + 64] + red[t + 128] + red[t + 192];
        nll[blockIdx.x * 64 + t] = logf(tot) - st[blockIdx.x * 64 + t];
    }
}

// ---- mean over rows -----------------------------------------------------
__global__ void k_final(const float* __restrict__ nll, float* __restrict__ out) {
    __shared__ float red[256];
    int t = threadIdx.x;
    float acc = 0.0f;
    for (int r = t; r < NROWS; r += 256) acc += nll[r];
    red[t] = acc;
    __syncthreads();
    #pragma unroll
    for (int off = 128; off > 0; off >>= 1) {
        if (t < off) red[t] += red[t + off];
        __syncthreads();
    }
    if (t == 0) out[0] = red[0] / (float)NROWS;
}

extern "C" void kernel_launch(void* const* d_in, const int* in_sizes, int n_in,
                              void* d_out, int out_size, void* d_ws, size_t ws_size,
                              hipStream_t stream) {
    const float* X = (const float*)d_in[0];
    const float* P = (const float*)d_in[1];
    const int*   T = (const int*)  d_in[3];   // d_in[2] = indices (unused)
    float* out = (float*)d_out;

    char* ws = (char*)d_ws;
    unsigned short* Xb = (unsigned short*)ws;                 // 512 KB
    float* st   = (float*)(ws + (512 << 10));                 // 16 KB
    float* nll  = (float*)(ws + (512 << 10) + (16 << 10));    // 16 KB
    float* psum = (float*)(ws + (1 << 20));                   // 8 MB (512 x 4096 f32)

    k_prep  <<<NROWS / 4, 256, 0, stream>>>(X, P, T, Xb, st);
    k_main  <<<NBLK, 512, 0, stream>>>(P, Xb, psum);
    k_rowred<<<NROWS / 64, 256, 0, stream>>>(psum, st, nll);
    k_final <<<1, 256, 0, stream>>>(nll, out);
}